// Round 13
// baseline (2731.038 us; speedup 1.0000x reference)
//
#include <hip/hip_runtime.h>
#include <math.h>

#define P_TOK 4096
#define T_TOK 1024
#define KV_TOK 5120
#define DIM 2048
#define VOCAB 32000
#define NHEAD 8
#define DHEAD 256
#define FFDIM 8192
#define NLAYER 2

using f32x4  = __attribute__((ext_vector_type(4))) float;
using bf16x4 = __attribute__((ext_vector_type(4))) __bf16;
using bf16x8 = __attribute__((ext_vector_type(8))) __bf16;

typedef const __attribute__((address_space(1))) void* gp1_t;
typedef __attribute__((address_space(3))) void* lp3_t;

__device__ __forceinline__ void gload16(const void* g, void* l) {
  __builtin_amdgcn_global_load_lds((gp1_t)g, (lp3_t)l, 16, 0, 0);
}

__device__ __forceinline__ unsigned pack_bf2(float a, float b) {
  union { __bf16 h[2]; unsigned u; } x;
  x.h[0] = (__bf16)a; x.h[1] = (__bf16)b; return x.u;
}

// gelu tanh-approx in sigmoid form: u*sigmoid(1.5957692*(u+0.044715u^3))
__device__ __forceinline__ float gelu_tanh(float u) {
  const float k2 = 1.5957691216057308f * (u + 0.044715f * u * u * u);
  return u / (1.0f + __expf(-k2));
}

// ---------------------------------------------------------------------------
// GEMM 128x128 (r9 schedule, known-good, plain stores): C[M,N] = A[M,K] @ B^T.
// Double-buffered LDS + counted vmcnt(8) + raw s_barrier (T4); T2 XOR-swizzle;
// T1 XCD swizzle M-fastest; restage hoisted above MFMA.
// ---------------------------------------------------------------------------
template<typename CT, bool ACCUM, int EPI>
__global__ __launch_bounds__(256) void gemm_bt(
    const __bf16* __restrict__ A, const __bf16* __restrict__ B, CT* __restrict__ C,
    int M, int N, int K, int lda, int ldb, int ldc)
{
  __shared__ __align__(16) __bf16 As[2][128][64];   // 2 x 16 KB
  __shared__ __align__(16) __bf16 Bs[2][128][64];
  const int tid = threadIdx.x;
  const int lane = tid & 63, wave = tid >> 6;

  int bx = blockIdx.x, by = blockIdx.y;
  {
    const int gx = gridDim.x, gy = gridDim.y;
    const int nwg = gx * gy;
    if ((nwg & 7) == 0) {
      const int lin = bx * gy + by;          // M varies fastest
      const int cpx = nwg >> 3;
      const int swz = (lin & 7) * cpx + (lin >> 3);
      bx = swz / gy; by = swz % gy;
    }
  }
  const int bm = by << 7, bn = bx << 7;

  const int fr = lane & 15, fq = lane >> 4;
  const int wm = (wave >> 1) << 6, wn = (wave & 1) << 6;
  const int l8 = lane >> 3;
  const int c8 = ((lane & 7) ^ l8) << 3;     // T2 pre-swizzled source granule
  const int sw = fr & 7;

  const __bf16* ga[4]; const __bf16* gb[4];
  char* la[4]; char* lb[4];
#pragma unroll
  for (int i = 0; i < 4; ++i) {
    const int c = (wave << 2) + i;
    const int row = (c << 3) + l8;
    ga[i] = A + (size_t)(bm + row) * lda + c8;
    gb[i] = B + (size_t)(bn + row) * ldb + c8;
    la[i] = (char*)(&As[0][0][0]) + (c << 10);
    lb[i] = (char*)(&Bs[0][0][0]) + (c << 10);
  }
  f32x4 acc[4][4] = {};
  const int nk = K >> 6;

#pragma unroll
  for (int i = 0; i < 4; ++i) { gload16(ga[i], la[i]); gload16(gb[i], lb[i]); }
#pragma unroll
  for (int i = 0; i < 4; ++i) { gload16(ga[i] + 64, la[i] + 16384); gload16(gb[i] + 64, lb[i] + 16384); }

  auto step = [&](const int buf, const int t) {
    if (t + 2 < nk) asm volatile("s_waitcnt vmcnt(8)" ::: "memory");
    else            asm volatile("s_waitcnt vmcnt(0)" ::: "memory");
    asm volatile("s_barrier" ::: "memory");
    bf16x8 a[2][4], b[2][4];
#pragma unroll
    for (int ks = 0; ks < 2; ++ks) {
      const int ce = (((ks << 2) + fq) ^ sw) << 3;
#pragma unroll
      for (int i = 0; i < 4; ++i) {
        a[ks][i] = *reinterpret_cast<const bf16x8*>(&As[buf][wm + (i << 4) + fr][ce]);
        b[ks][i] = *reinterpret_cast<const bf16x8*>(&Bs[buf][wn + (i << 4) + fr][ce]);
      }
    }
    asm volatile("s_waitcnt lgkmcnt(0)" ::: "memory");
    asm volatile("s_barrier" ::: "memory");
    if (t + 2 < nk) {
      const int k2 = (t + 2) << 6;
      const int lo = buf << 14;
#pragma unroll
      for (int i = 0; i < 4; ++i) {
        gload16(ga[i] + k2, la[i] + lo);
        gload16(gb[i] + k2, lb[i] + lo);
      }
    }
    __builtin_amdgcn_sched_barrier(0);
#pragma unroll
    for (int ks = 0; ks < 2; ++ks)
#pragma unroll
      for (int mi = 0; mi < 4; ++mi)
#pragma unroll
        for (int ni = 0; ni < 4; ++ni)
          acc[mi][ni] = __builtin_amdgcn_mfma_f32_16x16x32_bf16(a[ks][mi], b[ks][ni], acc[mi][ni], 0, 0, 0);
  };
  for (int t = 0; t < nk; t += 2) { step(0, t); step(1, t + 1); }

#pragma unroll
  for (int mi = 0; mi < 4; ++mi) {
#pragma unroll
    for (int r = 0; r < 4; ++r) {
      const size_t rowi = (size_t)(bm + wm + (mi << 4) + (fq << 2) + r);
      CT* Crow = C + rowi * ldc + bn + wn + fr;
#pragma unroll
      for (int ni = 0; ni < 4; ++ni) {
        float v = acc[mi][ni][r];
        if (EPI == 1) v = gelu_tanh(v);
        if (ACCUM) Crow[ni << 4] += (CT)v;
        else       Crow[ni << 4] = (CT)v;
      }
    }
  }
}

// ---------------------------------------------------------------------------
// GEMM 256x256 v3 (r12 post-mortem): 1024 threads / 16 waves, per-wave 64x64.
// acc[4][4] = 64 VGPR + split-ks frags 32 + addr ~25 => fits the 128-VGPR cap
// that 16-wave residency requires (r10/r11 failed with 224-reg demand at 512
// threads). Same r9 2-barrier schedule: counted vmcnt(4), T2 swizzle, m204
// XCD swizzle, restage above MFMA. LDS 128 KB, 1 block/CU, 4 waves/SIMD.
// Requires M%256==0, N%256==0, K%128==0, grid >= 256 blocks recommended.
// ---------------------------------------------------------------------------
template<typename CT, bool ACCUM, int EPI>
__global__ __launch_bounds__(1024, 4) void gemm256(
    const __bf16* __restrict__ A, const __bf16* __restrict__ B, CT* __restrict__ C,
    int M, int N, int K, int lda, int ldb, int ldc)
{
  __shared__ __align__(16) __bf16 As[2][256][64];   // 2 x 32 KB
  __shared__ __align__(16) __bf16 Bs[2][256][64];   // 2 x 32 KB
  const int tid = threadIdx.x;
  const int lane = tid & 63, wave = tid >> 6;       // wave 0..15

  // bijective XCD swizzle (m204), M-fastest decode
  const int nwg = gridDim.x;
  const int gy = M >> 8;
  const int q8 = nwg >> 3, r8 = nwg & 7;
  const int xcd = blockIdx.x & 7, idx = blockIdx.x >> 3;
  const int swz = (xcd < r8 ? xcd * (q8 + 1) : r8 * (q8 + 1) + (xcd - r8) * q8) + idx;
  const int bm = (swz % gy) << 8;
  const int bn = (swz / gy) << 8;

  const int fr = lane & 15, fq = lane >> 4;
  const int wm = (wave >> 2) << 6;           // M quarter (wave/4)
  const int wn = (wave & 3) << 6;            // N quarter
  const int rowq = tid >> 3;                 // 0..127: row within 128-row slice
  const int c8 = ((tid & 7) ^ (rowq & 7)) << 3;  // T2 pre-swizzled source granule
  const int sw = fr & 7;

  // staging: slice i (i=0,1) covers rows i*128 + rowq; dest wave-linear
  const __bf16* ga[2]; const __bf16* gb[2];
  char* la[2]; char* lb[2];
#pragma unroll
  for (int i = 0; i < 2; ++i) {
    ga[i] = A + (size_t)(bm + (i << 7) + rowq) * lda + c8;
    gb[i] = B + (size_t)(bn + (i << 7) + rowq) * ldb + c8;
    la[i] = (char*)(&As[0][0][0]) + (i << 14) + (wave << 10);
    lb[i] = (char*)(&Bs[0][0][0]) + (i << 14) + (wave << 10);
  }
  f32x4 acc[4][4] = {};
  const int nk = K >> 6;

  // prologue: tile0 -> buf0, tile1 -> buf1 (8 loads/thread in flight)
#pragma unroll
  for (int i = 0; i < 2; ++i) { gload16(ga[i], la[i]); gload16(gb[i], lb[i]); }
#pragma unroll
  for (int i = 0; i < 2; ++i) { gload16(ga[i] + 64, la[i] + 32768); gload16(gb[i] + 64, lb[i] + 32768); }

  auto step = [&](const int buf, const int t) {
    if (t + 2 < nk) asm volatile("s_waitcnt vmcnt(4)" ::: "memory");
    else            asm volatile("s_waitcnt vmcnt(0)" ::: "memory");
    asm volatile("s_barrier" ::: "memory");
    // ---- ks = 0: read 8 frags -> wait -> 16 MFMA ----
    {
      bf16x8 a[4], b[4];
      const int ce = (fq ^ sw) << 3;
#pragma unroll
      for (int i = 0; i < 4; ++i) {
        a[i] = *reinterpret_cast<const bf16x8*>(&As[buf][wm + (i << 4) + fr][ce]);
        b[i] = *reinterpret_cast<const bf16x8*>(&Bs[buf][wn + (i << 4) + fr][ce]);
      }
      asm volatile("s_waitcnt lgkmcnt(0)" ::: "memory");
      __builtin_amdgcn_sched_barrier(0);
#pragma unroll
      for (int mi = 0; mi < 4; ++mi)
#pragma unroll
        for (int ni = 0; ni < 4; ++ni)
          acc[mi][ni] = __builtin_amdgcn_mfma_f32_16x16x32_bf16(a[mi], b[ni], acc[mi][ni], 0, 0, 0);
      __builtin_amdgcn_sched_barrier(0);   // keep ks1 reads below (reg budget)
    }
    // ---- ks = 1: read 8 frags -> wait -> barrier -> restage -> 16 MFMA ----
    {
      bf16x8 a[4], b[4];
      const int ce = ((4 + fq) ^ sw) << 3;
#pragma unroll
      for (int i = 0; i < 4; ++i) {
        a[i] = *reinterpret_cast<const bf16x8*>(&As[buf][wm + (i << 4) + fr][ce]);
        b[i] = *reinterpret_cast<const bf16x8*>(&Bs[buf][wn + (i << 4) + fr][ce]);
      }
      asm volatile("s_waitcnt lgkmcnt(0)" ::: "memory");
      asm volatile("s_barrier" ::: "memory");     // all waves done reading buf
      if (t + 2 < nk) {
        const int k2 = (t + 2) << 6;
        const int lo = buf << 15;
#pragma unroll
        for (int i = 0; i < 2; ++i) {
          gload16(ga[i] + k2, la[i] + lo);
          gload16(gb[i] + k2, lb[i] + lo);
        }
      }
      __builtin_amdgcn_sched_barrier(0);          // pin stage-issue above MFMA
#pragma unroll
      for (int mi = 0; mi < 4; ++mi)
#pragma unroll
        for (int ni = 0; ni < 4; ++ni)
          acc[mi][ni] = __builtin_amdgcn_mfma_f32_16x16x32_bf16(a[mi], b[ni], acc[mi][ni], 0, 0, 0);
    }
  };
  for (int t = 0; t < nk; t += 2) { step(0, t); step(1, t + 1); }

  // epilogue
#pragma unroll
  for (int mi = 0; mi < 4; ++mi) {
#pragma unroll
    for (int r = 0; r < 4; ++r) {
      const size_t rowi = (size_t)(bm + wm + (mi << 4) + (fq << 2) + r);
      CT* Crow = C + rowi * ldc + bn + wn + fr;
#pragma unroll
      for (int ni = 0; ni < 4; ++ni) {
        float v = acc[mi][ni][r];
        if (EPI == 1) v = gelu_tanh(v);
        if (ACCUM) Crow[ni << 4] += (CT)v;
        else       Crow[ni << 4] = (CT)v;
      }
    }
  }
}

// ---------------------------------------------------------------------------
// Fused flash attention with block-sparse tile skipping (unchanged, verified).
// ---------------------------------------------------------------------------
template<int MODE>
__global__ __launch_bounds__(256, 2) void flash_attn(
    const __bf16* __restrict__ Q, int ldq,
    const __bf16* __restrict__ K, int ldk,
    const __bf16* __restrict__ VT, int lenKV,
    __bf16* __restrict__ Oout, int ldo,
    const int* __restrict__ pb, const int* __restrict__ pp,
    const int* __restrict__ tb, const int* __restrict__ tp)
{
  __shared__ __align__(16) char KsB[64 * 512];
  __shared__ __align__(16) char VtsB[256 * 128];
  __shared__ __align__(16) char PsB[64 * 128];
  const int tid = threadIdx.x;
  const int lane = tid & 63, wave = tid >> 6;
  const int fr = lane & 15, fq = lane >> 4;
  const int sw7 = fr & 7;
  const int q0 = blockIdx.x << 6;
  const int h = blockIdx.y;
  const __bf16* Qh = Q + (size_t)h * DHEAD;
  const __bf16* Kh = K + (size_t)h * DHEAD;
  const __bf16* VTh = VT + (size_t)h * DHEAD * lenKV;

  int qb_l, aux_l;
  if (MODE == 0) { qb_l = pb[q0 + lane]; aux_l = pp[q0 + lane]; }
  else           { qb_l = tb[q0 + lane]; aux_l = tp[((q0 + lane) >> 4) << 4]; }
  const int qb0 = __shfl(qb_l, 0);
  const bool uniform = __all(qb_l == qb0);
  int amax = aux_l;
#pragma unroll
  for (int s = 1; s < 64; s <<= 1) amax = max(amax, __shfl_xor(amax, s));

  const int q_s = q0 + (wave << 4) + fr;
  int qb_s, aux_s;
  if (MODE == 0) { qb_s = pb[q_s]; aux_s = pp[q_s]; }
  else           { qb_s = tb[q_s]; aux_s = tp[(q_s >> 4) << 4]; }
  const int qblk_s = q_s >> 4;

  bf16x8 qreg[8];
#pragma unroll
  for (int ds = 0; ds < 8; ++ds)
    qreg[ds] = *reinterpret_cast<const bf16x8*>(
        Qh + (size_t)q_s * ldq + (ds << 5) + (fq << 3));

  f32x4 acc[16] = {};
  float mrun = -1.0e30f, lrun = 0.0f;

  for (int kv0 = 0; kv0 < lenKV; kv0 += 64) {
    bool ok;
    if (MODE == 0) {
      ok = (pb[kv0 + lane] == qb0) && (pp[kv0 + lane] <= amax);
    } else if (kv0 < P_TOK) {
      ok = (pb[kv0 + lane] == qb0) && (pp[kv0 + lane] < amax);
    } else {
      const int kk = kv0 - P_TOK + lane;
      const int kb = kk >> 4;
      ok = (tb[kk] == qb0) && (kb >= (q0 >> 4)) && (kb <= ((q0 + 63) >> 4));
    }
    if (uniform && !__any(ok)) continue;

    __syncthreads();
#pragma unroll
    for (int i = 0; i < 8; ++i) {
      const int s = wave + (i << 2);
      const int cl = (s << 6) + lane;
      {
        const int r = cl >> 5, c = cl & 31;
        gload16(Kh + (size_t)(kv0 + r) * ldk + ((c ^ (r & 7)) << 3), KsB + (s << 10));
      }
      {
        const int rd = cl >> 3, c = cl & 7;
        gload16(VTh + (size_t)rd * lenKV + kv0 + ((c ^ (rd & 7)) << 3), VtsB + (s << 10));
      }
    }
    __syncthreads();

    f32x4 st[4] = {};
#pragma unroll
    for (int ds = 0; ds < 8; ++ds) {
#pragma unroll
      for (int mt = 0; mt < 4; ++mt) {
        const bf16x8 kf = *reinterpret_cast<const bf16x8*>(
            KsB + ((mt << 4) + fr) * 512 + ((((ds << 2) + fq) ^ sw7) << 4));
        st[mt] = __builtin_amdgcn_mfma_f32_16x16x32_bf16(kf, qreg[ds], st[mt], 0, 0, 0);
      }
    }

    float pv[16];
    float tmax = -3.0e38f;
#pragma unroll
    for (int mt = 0; mt < 4; ++mt) {
      const int kbase = kv0 + (mt << 4) + (fq << 2);
      bool vis[4];
      if (MODE == 0) {
        const int4 pbv = *reinterpret_cast<const int4*>(pb + kbase);
        const int4 ppv = *reinterpret_cast<const int4*>(pp + kbase);
        vis[0] = (pbv.x == qb_s) && (aux_s >= ppv.x);
        vis[1] = (pbv.y == qb_s) && (aux_s >= ppv.y);
        vis[2] = (pbv.z == qb_s) && (aux_s >= ppv.z);
        vis[3] = (pbv.w == qb_s) && (aux_s >= ppv.w);
      } else if (kv0 < P_TOK) {
        const int4 pbv = *reinterpret_cast<const int4*>(pb + kbase);
        const int4 ppv = *reinterpret_cast<const int4*>(pp + kbase);
        vis[0] = (pbv.x == qb_s) && (aux_s > ppv.x);
        vis[1] = (pbv.y == qb_s) && (aux_s > ppv.y);
        vis[2] = (pbv.z == qb_s) && (aux_s > ppv.z);
        vis[3] = (pbv.w == qb_s) && (aux_s > ppv.w);
      } else {
        const int4 tbv = *reinterpret_cast<const int4*>(tb + kbase - P_TOK);
        const bool blkok = (((kv0 - P_TOK) >> 4) + mt) == qblk_s;
        vis[0] = (tbv.x == qb_s) && blkok;
        vis[1] = (tbv.y == qb_s) && blkok;
        vis[2] = (tbv.z == qb_s) && blkok;
        vis[3] = (tbv.w == qb_s) && blkok;
      }
#pragma unroll
      for (int r = 0; r < 4; ++r) {
        const float sv = st[mt][r] * 0.0625f;
        const float val = vis[r] ? sv : -1.0e30f;
        pv[(mt << 2) + r] = val;
        tmax = fmaxf(tmax, val);
      }
    }
    tmax = fmaxf(tmax, __shfl_xor(tmax, 16));
    tmax = fmaxf(tmax, __shfl_xor(tmax, 32));

    const float m_old = mrun;
    const bool grow = tmax > m_old + 8.0f;
    const float mnew = grow ? tmax : m_old;
    float tsum = 0.f;
#pragma unroll
    for (int i = 0; i < 16; ++i) { pv[i] = __expf(pv[i] - mnew); tsum += pv[i]; }
    tsum += __shfl_xor(tsum, 16);
    tsum += __shfl_xor(tsum, 32);
    const float fac = __expf(m_old - mnew);
    lrun = lrun * fac + tsum;
    mrun = mnew;

#pragma unroll
    for (int mt = 0; mt < 4; ++mt) {
#pragma unroll
      for (int rp = 0; rp < 4; rp += 2) {
        const unsigned u = pack_bf2(pv[(mt << 2) + rp], pv[(mt << 2) + rp + 1]);
        *reinterpret_cast<unsigned*>(PsB + ((wave << 4) + fr) * 128
            + ((((mt << 1) + (fq >> 1)) ^ sw7) << 4) + ((fq & 1) << 3) + ((rp >> 1) << 2)) = u;
      }
    }

    if (!__all(!grow)) {
#pragma unroll
      for (int r = 0; r < 4; ++r) {
        const float f_r = __shfl(fac, ((lane >> 4) << 2) + r);
#pragma unroll
        for (int dt = 0; dt < 16; ++dt) acc[dt][r] *= f_r;
      }
    }

#pragma unroll
    for (int kk = 0; kk < 2; ++kk) {
      const bf16x8 pa = *reinterpret_cast<const bf16x8*>(
          PsB + ((wave << 4) + fr) * 128 + ((((kk << 2) + fq) ^ sw7) << 4));
#pragma unroll
      for (int dt = 0; dt < 16; ++dt) {
        const bf16x8 vb = *reinterpret_cast<const bf16x8*>(
            VtsB + ((dt << 4) + fr) * 128 + ((((kk << 2) + fq) ^ sw7) << 4));
        acc[dt] = __builtin_amdgcn_mfma_f32_16x16x32_bf16(pa, vb, acc[dt], 0, 0, 0);
      }
    }
  }

#pragma unroll
  for (int r = 0; r < 4; ++r) {
    const float linv = 1.0f / __shfl(lrun, ((lane >> 4) << 2) + r);
    const int rowg = q0 + (wave << 4) + (fq << 2) + r;
#pragma unroll
    for (int dt = 0; dt < 16; ++dt)
      Oout[(size_t)rowg * ldo + (size_t)h * DHEAD + (dt << 4) + fr] = (__bf16)(acc[dt][r] * linv);
  }
}

// ---------------------------------------------------------------------------
// Batched weight-set transpose: one dispatch per weight set.
// ---------------------------------------------------------------------------
__global__ __launch_bounds__(256) void transpose_set(
    const float* __restrict__ sQkv, const float* __restrict__ sO,
    const float* __restrict__ sM1, const float* __restrict__ sM2,
    __bf16* __restrict__ dstBase)
{
  int b = blockIdx.x;
  const float* src; long doff; int R, Cc;
  if (b < 12288)      { src = sQkv; R = DIM;   Cc = 3 * DIM; doff = 0; }
  else if (b < 16384) { b -= 12288; src = sO;  R = DIM; Cc = DIM;
                        doff = (long)3 * DIM * DIM; }
  else if (b < 32768) { b -= 16384; src = sM1; R = DIM; Cc = FFDIM;
                        doff = (long)3 * DIM * DIM + (long)DIM * DIM; }
  else                { b -= 32768; src = sM2; R = FFDIM; Cc = DIM;
                        doff = (long)3 * DIM * DIM + (long)DIM * DIM + (long)DIM * FFDIM; }
  __bf16* dst = dstBase + doff;
  const int tilesX = Cc >> 5;
  const int bx = (b % tilesX) << 5, by = (b / tilesX) << 5;
  __shared__ float tile[32][33];
  const int tx = threadIdx.x & 31, ty = threadIdx.x >> 5;
#pragma unroll
  for (int k = 0; k < 32; k += 8)
    tile[ty + k][tx] = src[(size_t)(by + ty + k) * Cc + bx + tx];
  __syncthreads();
#pragma unroll
  for (int k = 0; k < 32; k += 8)
    dst[(size_t)(bx + ty + k) * R + by + tx] = (__bf16)tile[tx][ty + k];
}

__global__ __launch_bounds__(256) void conv_bf16(const float* __restrict__ src,
    __bf16* __restrict__ dst, long n8)
{
  const long i = (long)blockIdx.x * 256 + threadIdx.x;
  if (i >= n8) return;
  const float4 a = reinterpret_cast<const float4*>(src)[i * 2];
  const float4 b = reinterpret_cast<const float4*>(src)[i * 2 + 1];
  bf16x8 h;
  h[0] = (__bf16)a.x; h[1] = (__bf16)a.y; h[2] = (__bf16)a.z; h[3] = (__bf16)a.w;
  h[4] = (__bf16)b.x; h[5] = (__bf16)b.y; h[6] = (__bf16)b.z; h[7] = (__bf16)b.w;
  reinterpret_cast<bf16x8*>(dst)[i] = h;
}

__global__ __launch_bounds__(256) void rms_bf16(const float* __restrict__ x,
    const float* __restrict__ g, __bf16* __restrict__ y, const int* __restrict__ row_idx)
{
  __shared__ float red[256];
  const int r = blockIdx.x;
  const int src = row_idx ? row_idx[r] : r;
  const float* xr = x + (size_t)src * DIM;
  __bf16* yr = y + (size_t)r * DIM;
  const int t = threadIdx.x;
  const float4 v0 = *reinterpret_cast<const float4*>(xr + t * 8);
  const float4 v1 = *reinterpret_cast<const float4*>(xr + t * 8 + 4);
  float ss = v0.x * v0.x + v0.y * v0.y + v0.z * v0.z + v0.w * v0.w
           + v1.x * v1.x + v1.y * v1.y + v1.z * v1.z + v1.w * v1.w;
  red[t] = ss; __syncthreads();
  for (int s = 128; s > 0; s >>= 1) { if (t < s) red[t] += red[t + s]; __syncthreads(); }
  const float inv = rsqrtf(red[0] * (1.0f / DIM) + 1e-6f);
  const float4 g0 = *reinterpret_cast<const float4*>(g + t * 8);
  const float4 g1 = *reinterpret_cast<const float4*>(g + t * 8 + 4);
  bf16x8 h;
  h[0] = (__bf16)(v0.x * g0.x * inv); h[1] = (__bf16)(v0.y * g0.y * inv);
  h[2] = (__bf16)(v0.z * g0.z * inv); h[3] = (__bf16)(v0.w * g0.w * inv);
  h[4] = (__bf16)(v1.x * g1.x * inv); h[5] = (__bf16)(v1.y * g1.y * inv);
  h[6] = (__bf16)(v1.z * g1.z * inv); h[7] = (__bf16)(v1.w * g1.w * inv);
  *reinterpret_cast<bf16x8*>(yr + t * 8) = h;
}

__global__ __launch_bounds__(256) void gather_rows_kernel(const float* __restrict__ tab,
    const int* __restrict__ ids, float* __restrict__ out)
{
  const int r = blockIdx.x;
  const float* src = tab + (size_t)ids[r] * DIM;
  float* dst = out + (size_t)r * DIM;
  const int t = threadIdx.x;
  *reinterpret_cast<float4*>(dst + t * 8) = *reinterpret_cast<const float4*>(src + t * 8);
  *reinterpret_cast<float4*>(dst + t * 8 + 4) = *reinterpret_cast<const float4*>(src + t * 8 + 4);
}

// ---------------------------------------------------------------------------
__global__ __launch_bounds__(256) void teacher_softmax_kernel(const float* __restrict__ TL,
    __bf16* __restrict__ PT, float* __restrict__ ENT, float* __restrict__ S1)
{
  __shared__ float sm[256], ss[256];
  const int r = blockIdx.x, t = threadIdx.x;
  const float* tl = TL + (size_t)r * VOCAB;
  __bf16* pt = PT + (size_t)r * VOCAB;
  float m = -3.0e38f, s = 0.f;
  for (int v = t; v < VOCAB; v += 256) {
    const float x = tl[v];
    if (x > m) { s = s * expf(m - x) + 1.f; m = x; }
    else       { s += expf(x - m); }
  }
  sm[t] = m; ss[t] = s; __syncthreads();
  for (int st = 128; st > 0; st >>= 1) {
    if (t < st) {
      const float m2 = sm[t + st], s2 = ss[t + st];
      const float M = fmaxf(sm[t], m2);
      ss[t] = ss[t] * expf(sm[t] - M) + s2 * expf(m2 - M);
      sm[t] = M;
    }
    __syncthreads();
  }
  const float Mt = sm[0], Z = ss[0];
  const float invZ = 1.0f / Z, lZ = logf(Z);
  __syncthreads();
  float ent = 0.f, s1 = 0.f;
  for (int v = t; v < VOCAB; v += 256) {
    const float x = tl[v];
    const float p = expf(x - Mt) * invZ;
    const __bf16 pb_ = (__bf16)p;
    pt[v] = pb_;
    const float pf = (float)pb_;
    ent += pf * (x - Mt - lZ);
    s1 += pf;
  }
  sm[t] = ent; ss[t] = s1; __syncthreads();
  for (int st = 128; st > 0; st >>= 1) {
    if (t < st) { sm[t] += sm[t + st]; ss[t] += ss[t + st]; }
    __syncthreads();
  }
  if (t == 0) { ENT[r] = sm[0]; S1[r] = ss[0]; }
}

// KD loss, single pass over DL: online-LSE + cross-term simultaneously.
__global__ __launch_bounds__(256) void kl_loss_kernel(const float* __restrict__ DL,
    const __bf16* __restrict__ PT, const float* __restrict__ ENT, const float* __restrict__ S1,
    const int* __restrict__ labels, const int* __restrict__ nitems, float* __restrict__ out)
{
  __shared__ float sm[256], ss[256], sc[256];
  const int r = blockIdx.x, t = threadIdx.x;
  if (labels[r] == -100) return;
  const float* dl = DL + (size_t)r * VOCAB;
  const __bf16* pt = PT + (size_t)r * VOCAB;
  float m = -3.0e38f, s = 0.f, cross = 0.f;
  for (int v = t; v < VOCAB; v += 256) {
    const float x = dl[v];
    cross += (float)pt[v] * x;
    if (x > m) { s = s * expf(m - x) + 1.f; m = x; }
    else       { s += expf(x - m); }
  }
  sm[t] = m; ss[t] = s; sc[t] = cross; __syncthreads();
  for (int st = 128; st > 0; st >>= 1) {
    if (t < st) {
      const float m2 = sm[t + st], s2 = ss[t + st];
      const float M = fmaxf(sm[t], m2);
      ss[t] = ss[t] * expf(sm[t] - M) + s2 * expf(m2 - M);
      sm[t] = M;
      sc[t] += sc[t + st];
    }
    __syncthreads();
  }
  if (t == 0) {
    const float lses = sm[0] + logf(ss[0]);
    const int raw = nitems[0];
    const float n = (raw > 0 && raw < 1000000) ? (float)raw : __int_as_float(raw);
    const float loss_r = ENT[r] - sc[0] + lses * S1[r];
    atomicAdd(out, loss_r / n);
  }
}

// ---------------------------------------------------------------------------
template<typename CT, bool ACCUM, int EPI>
static inline void g128(const __bf16* A, const __bf16* B, CT* C,
                        int M, int N, int K, int lda, int ldb, int ldc, hipStream_t s)
{
  gemm_bt<CT, ACCUM, EPI><<<dim3(N / 128, M / 128), 256, 0, s>>>(A, B, C, M, N, K, lda, ldb, ldc);
}
template<typename CT, bool ACCUM, int EPI>
static inline void g256(const __bf16* A, const __bf16* B, CT* C,
                        int M, int N, int K, int lda, int ldb, int ldc, hipStream_t s)
{
  gemm256<CT, ACCUM, EPI><<<dim3((M >> 8) * (N >> 8)), 1024, 0, s>>>(A, B, C, M, N, K, lda, ldb, ldc);
}

extern "C" void kernel_launch(void* const* d_in, const int* in_sizes, int n_in,
                              void* d_out, int out_size, void* d_ws, size_t ws_size,
                              hipStream_t stream)
{
  const int* prefix_ids = (const int*)d_in[0];
  const int* pb        = (const int*)d_in[1];
  const int* pp        = (const int*)d_in[2];
  const int* input_ids = (const int*)d_in[3];
  const int* tb        = (const int*)d_in[4];
  const int* tp        = (const int*)d_in[5];
  const int* tgi       = (const int*)d_in[6];
  const int* labels    = (const int*)d_in[7];
  const int* nitems    = (const int*)d_in[8];
  const float* Wt_embed = (const float*)d_in[9];
  const float* Wt_qkv   = (const float*)d_in[10];
  const float* Wt_o     = (const float*)d_in[11];
  const float* Wt_m1    = (const float*)d_in[12];
  const float* Wt_m2    = (const float*)d_in[13];
  const float* gt_ln1   = (const float*)d_in[14];
  const float* gt_ln2   = (const float*)d_in[15];
  const float* gt_lnf   = (const float*)d_in[16];
  const float* Wd_embed = (const float*)d_in[17];
  const float* Wd_qkv   = (const float*)d_in[18];
  const float* Wd_o     = (const float*)d_in[19];
  const float* Wd_m1    = (const float*)d_in[20];
  const float* Wd_m2    = (const float*)d_in[21];
  const float* gd_ln1   = (const float*)d_in[22];
  const float* gd_ln2   = (const float*)d_in[23];
  const float* gd_lnf   = (const float*)d_in[24];

  // ---------------- workspace layout (bytes) ----------------
  char* base = (char*)d_ws;
  size_t off = 0;
  auto alloc = [&](size_t bytes) { size_t o = off; off += (bytes + 255) & ~(size_t)255; return o; };
  const size_t oX    = alloc((size_t)P_TOK * DIM * 4);
  const size_t oXNb  = alloc((size_t)KV_TOK * DIM * 2);
  const size_t oQKVb = alloc((size_t)P_TOK * 3 * DIM * 2);
  const size_t oOb   = alloc((size_t)P_TOK * DIM * 2);
  const size_t oVT   = alloc((size_t)DIM * KV_TOK * 2);
  const size_t oMHb  = alloc((size_t)P_TOK * FFDIM * 2);
  const size_t oY    = alloc((size_t)T_TOK * DIM * 4);
  const size_t oPT   = alloc((size_t)T_TOK * VOCAB * 2);
  const size_t oENT  = alloc((size_t)T_TOK * 4);
  const size_t oS1   = alloc((size_t)T_TOK * 4);
  const size_t oEMB  = alloc((size_t)VOCAB * DIM * 2);
  const size_t oWB   = alloc((size_t)(3 * DIM * DIM + DIM * DIM + DIM * FFDIM + FFDIM * DIM) * 2);
  if (ws_size < off) return;

  float*  X    = (float*)(base + oX);
  __bf16* XNb  = (__bf16*)(base + oXNb);
  __bf16* QKVb = (__bf16*)(base + oQKVb);
  __bf16* Ob   = (__bf16*)(base + oOb);
  __bf16* VT   = (__bf16*)(base + oVT);
  __bf16* MHb  = (__bf16*)(base + oMHb);
  float*  Y    = (float*)(base + oY);
  __bf16* PT   = (__bf16*)(base + oPT);
  float*  ENT  = (float*)(base + oENT);
  float*  S1   = (float*)(base + oS1);
  __bf16* embB = (__bf16*)(base + oEMB);
  __bf16* wQkvT = (__bf16*)(base + oWB);                 // [3D, D] rows: q | k | v
  __bf16* wOT   = wQkvT + (size_t)3 * DIM * DIM;         // [D, D]
  __bf16* wM1T  = wOT + (size_t)DIM * DIM;               // [FF, D]
  __bf16* wM2T  = wM1T + (size_t)FFDIM * DIM;            // [D, FF]
  float*  TLOG = (float*)(base + oQKVb);   // overlay (QKVb..MHb dead at logit time)
  float*  DLOG = (float*)(base + oQKVb);

  hipMemsetAsync(d_out, 0, sizeof(float), stream);

  // ---------------- target causal prefill ----------------
  gather_rows_kernel<<<P_TOK, 256, 0, stream>>>(Wt_embed, prefix_ids, X);
  for (int l = 0; l < NLAYER; ++l) {
    transpose_set<<<49152, 256, 0, stream>>>(
        Wt_qkv + (size_t)l * DIM * 3 * DIM, Wt_o + (size_t)l * DIM * DIM,
        Wt_m1 + (size_t)l * DIM * FFDIM, Wt_m2 + (size_t)l * FFDIM * DIM, wQkvT);

    rms_bf16<<<P_TOK, 256, 0, stream>>>(X, gt_ln1 + l * DIM, XNb, nullptr);
    // QK: [P, 2D] (q | k); V^T directly via GEMM
    g256<__bf16, false, 0>(XNb, wQkvT, QKVb, P_TOK, 2 * DIM, DIM, DIM, DIM, 2 * DIM, stream);
    g128<__bf16, false, 0>(wQkvT + (size_t)2 * DIM * DIM, XNb, VT,
                           DIM, P_TOK, DIM, DIM, DIM, P_TOK, stream);           // VT [D, P]
    flash_attn<0><<<dim3(P_TOK / 64, NHEAD), 256, 0, stream>>>(
        QKVb, 2 * DIM, QKVb + DIM, 2 * DIM, VT, P_TOK, Ob, DIM, pb, pp, nullptr, nullptr);
    g128<float, true, 0>(Ob, wOT, X, P_TOK, DIM, DIM, DIM, DIM, DIM, stream);   // X += attn@Wo
    rms_bf16<<<P_TOK, 256, 0, stream>>>(X, gt_ln2 + l * DIM, XNb, nullptr);
    g256<__bf16, false, 1>(XNb, wM1T, MHb, P_TOK, FFDIM, DIM, DIM, DIM, FFDIM, stream); // +gelu
    g128<float, true, 0>(MHb, wM2T, X, P_TOK, DIM, FFDIM, FFDIM, FFDIM, DIM, stream);   // X += mlp
  }

  // ---------------- teacher logits -> PT/ENT/S1 ----------------
  rms_bf16<<<T_TOK, 256, 0, stream>>>(X, gt_lnf, XNb, tgi);
  conv_bf16<<<((long)VOCAB * DIM / 8 + 255) / 256, 256, 0, stream>>>(Wt_embed, embB, (long)VOCAB * DIM / 8);
  g256<float, false, 0>(XNb, embB, TLOG, T_TOK, VOCAB, DIM, DIM, DIM, VOCAB, stream);
  teacher_softmax_kernel<<<T_TOK, 256, 0, stream>>>(TLOG, PT, ENT, S1);

  // ---------------- draft forward ----------------
  gather_rows_kernel<<<T_TOK, 256, 0, stream>>>(Wd_embed, input_ids, Y);
  transpose_set<<<49152, 256, 0, stream>>>(Wd_qkv, Wd_o, Wd_m1, Wd_m2, wQkvT);

  rms_bf16<<<P_TOK, 256, 0, stream>>>(X, gd_ln1, XNb, nullptr);                       // xkv_n[0:P]
  rms_bf16<<<T_TOK, 256, 0, stream>>>(Y, gd_ln1, XNb + (size_t)P_TOK * DIM, nullptr); // xq_n
  __bf16* Qb = QKVb;                                 // [T, D]
  __bf16* Kb = QKVb + (size_t)T_TOK * DIM;           // [KV, D]
  g128<__bf16, false, 0>(XNb + (size_t)P_TOK * DIM, wQkvT, Qb, T_TOK, DIM, DIM, DIM, DIM, DIM, stream);
  g128<__bf16, false, 0>(XNb, wQkvT + (size_t)DIM * DIM, Kb, KV_TOK, DIM, DIM, DIM, DIM, DIM, stream);
  g128<__bf16, false, 0>(wQkvT + (size_t)2 * DIM * DIM, XNb, VT,
                         DIM, KV_TOK, DIM, DIM, DIM, KV_TOK, stream);           // VTd [D, KV]
  flash_attn<1><<<dim3(T_TOK / 64, NHEAD), 256, 0, stream>>>(
      Qb, DIM, Kb, DIM, VT, KV_TOK, Ob, DIM, pb, pp, tb, tp);
  g128<float, true, 0>(Ob, wOT, Y, T_TOK, DIM, DIM, DIM, DIM, DIM, stream);     // y = xq + attn@Wo
  rms_bf16<<<T_TOK, 256, 0, stream>>>(Y, gd_ln2, XNb, nullptr);
  g128<__bf16, false, 1>(XNb, wM1T, MHb, T_TOK, FFDIM, DIM, DIM, DIM, FFDIM, stream);  // +gelu
  g128<float, true, 0>(MHb, wM2T, Y, T_TOK, DIM, FFDIM, FFDIM, FFDIM, DIM, stream);    // y += mlp
  rms_bf16<<<T_TOK, 256, 0, stream>>>(Y, gd_lnf, XNb, nullptr);
  conv_bf16<<<((long)VOCAB * DIM / 8 + 255) / 256, 256, 0, stream>>>(Wd_embed, embB, (long)VOCAB * DIM / 8);
  g256<float, false, 0>(XNb, embB, DLOG, T_TOK, VOCAB, DIM, DIM, DIM, VOCAB, stream);

  // ---------------- KD loss ----------------
  kl_loss_kernel<<<T_TOK, 256, 0, stream>>>(DLOG, PT, ENT, S1, labels, nitems, (float*)d_out);
}

// Round 14
// 2480.049 us; speedup vs baseline: 1.1012x; 1.1012x over previous
//
#include <hip/hip_runtime.h>
#include <math.h>

#define P_TOK 4096
#define T_TOK 1024
#define KV_TOK 5120
#define DIM 2048
#define VOCAB 32000
#define NHEAD 8
#define DHEAD 256
#define FFDIM 8192
#define NLAYER 2

using f32x4  = __attribute__((ext_vector_type(4))) float;
using bf16x4 = __attribute__((ext_vector_type(4))) __bf16;
using bf16x8 = __attribute__((ext_vector_type(8))) __bf16;

typedef const __attribute__((address_space(1))) void* gp1_t;
typedef __attribute__((address_space(3))) void* lp3_t;

__device__ __forceinline__ void gload16(const void* g, void* l) {
  __builtin_amdgcn_global_load_lds((gp1_t)g, (lp3_t)l, 16, 0, 0);
}

__device__ __forceinline__ unsigned pack_bf2(float a, float b) {
  union { __bf16 h[2]; unsigned u; } x;
  x.h[0] = (__bf16)a; x.h[1] = (__bf16)b; return x.u;
}

// gelu tanh-approx in sigmoid form: u*sigmoid(1.5957692*(u+0.044715u^3))
__device__ __forceinline__ float gelu_tanh(float u) {
  const float k2 = 1.5957691216057308f * (u + 0.044715f * u * u * u);
  return u / (1.0f + __expf(-k2));
}

// ---------------------------------------------------------------------------
// GEMM 128x128 (r9 schedule, best measured): C[M,N] = A[M,K] @ B^T.
// Double-buffered LDS + counted vmcnt(8) + raw s_barrier (T4); T2 XOR-swizzle
// (both-sides); T1 XCD swizzle M-fastest; restage hoisted above MFMA.
// r9 measured: 176 us @ logits shape, MfmaUtil 31, bank conflicts 0.
// 256^2-tile variants (r10/r11/r13) all spilled (compiler reg-budget) — keep 128^2.
// ---------------------------------------------------------------------------
template<typename CT, bool ACCUM, int EPI>
__global__ __launch_bounds__(256) void gemm_bt(
    const __bf16* __restrict__ A, const __bf16* __restrict__ B, CT* __restrict__ C,
    int M, int N, int K, int lda, int ldb, int ldc)
{
  __shared__ __align__(16) __bf16 As[2][128][64];   // 2 x 16 KB
  __shared__ __align__(16) __bf16 Bs[2][128][64];
  const int tid = threadIdx.x;
  const int lane = tid & 63, wave = tid >> 6;

  int bx = blockIdx.x, by = blockIdx.y;
  {
    const int gx = gridDim.x, gy = gridDim.y;
    const int nwg = gx * gy;
    if ((nwg & 7) == 0) {
      const int lin = bx * gy + by;          // M varies fastest
      const int cpx = nwg >> 3;
      const int swz = (lin & 7) * cpx + (lin >> 3);
      bx = swz / gy; by = swz % gy;
    }
  }
  const int bm = by << 7, bn = bx << 7;

  const int fr = lane & 15, fq = lane >> 4;
  const int wm = (wave >> 1) << 6, wn = (wave & 1) << 6;
  const int l8 = lane >> 3;
  const int c8 = ((lane & 7) ^ l8) << 3;     // T2 pre-swizzled source granule
  const int sw = fr & 7;

  const __bf16* ga[4]; const __bf16* gb[4];
  char* la[4]; char* lb[4];
#pragma unroll
  for (int i = 0; i < 4; ++i) {
    const int c = (wave << 2) + i;
    const int row = (c << 3) + l8;
    ga[i] = A + (size_t)(bm + row) * lda + c8;
    gb[i] = B + (size_t)(bn + row) * ldb + c8;
    la[i] = (char*)(&As[0][0][0]) + (c << 10);
    lb[i] = (char*)(&Bs[0][0][0]) + (c << 10);
  }
  f32x4 acc[4][4] = {};
  const int nk = K >> 6;

#pragma unroll
  for (int i = 0; i < 4; ++i) { gload16(ga[i], la[i]); gload16(gb[i], lb[i]); }
#pragma unroll
  for (int i = 0; i < 4; ++i) { gload16(ga[i] + 64, la[i] + 16384); gload16(gb[i] + 64, lb[i] + 16384); }

  auto step = [&](const int buf, const int t) {
    if (t + 2 < nk) asm volatile("s_waitcnt vmcnt(8)" ::: "memory");
    else            asm volatile("s_waitcnt vmcnt(0)" ::: "memory");
    asm volatile("s_barrier" ::: "memory");    // buf's slices visible to all
    bf16x8 a[2][4], b[2][4];
#pragma unroll
    for (int ks = 0; ks < 2; ++ks) {
      const int ce = (((ks << 2) + fq) ^ sw) << 3;
#pragma unroll
      for (int i = 0; i < 4; ++i) {
        a[ks][i] = *reinterpret_cast<const bf16x8*>(&As[buf][wm + (i << 4) + fr][ce]);
        b[ks][i] = *reinterpret_cast<const bf16x8*>(&Bs[buf][wn + (i << 4) + fr][ce]);
      }
    }
    asm volatile("s_waitcnt lgkmcnt(0)" ::: "memory");  // reads complete
    asm volatile("s_barrier" ::: "memory");             // ... in all waves
    if (t + 2 < nk) {                          // restage buf with tile t+2 NOW
      const int k2 = (t + 2) << 6;             // (overlaps the MFMA below)
      const int lo = buf << 14;
#pragma unroll
      for (int i = 0; i < 4; ++i) {
        gload16(ga[i] + k2, la[i] + lo);
        gload16(gb[i] + k2, lb[i] + lo);
      }
    }
    __builtin_amdgcn_sched_barrier(0);         // pin stage-issue above MFMA
#pragma unroll
    for (int ks = 0; ks < 2; ++ks)
#pragma unroll
      for (int mi = 0; mi < 4; ++mi)
#pragma unroll
        for (int ni = 0; ni < 4; ++ni)
          acc[mi][ni] = __builtin_amdgcn_mfma_f32_16x16x32_bf16(a[ks][mi], b[ks][ni], acc[mi][ni], 0, 0, 0);
  };
  for (int t = 0; t < nk; t += 2) { step(0, t); step(1, t + 1); }

  // epilogue (plain stores — NT stores regressed in r12)
#pragma unroll
  for (int mi = 0; mi < 4; ++mi) {
#pragma unroll
    for (int r = 0; r < 4; ++r) {
      const size_t rowi = (size_t)(bm + wm + (mi << 4) + (fq << 2) + r);
      CT* Crow = C + rowi * ldc + bn + wn + fr;
#pragma unroll
      for (int ni = 0; ni < 4; ++ni) {
        float v = acc[mi][ni][r];
        if (EPI == 1) v = gelu_tanh(v);
        if (ACCUM) Crow[ni << 4] += (CT)v;
        else       Crow[ni << 4] = (CT)v;
      }
    }
  }
}

// ---------------------------------------------------------------------------
// Fused flash attention with block-sparse tile skipping (unchanged, verified).
// ---------------------------------------------------------------------------
template<int MODE>
__global__ __launch_bounds__(256, 2) void flash_attn(
    const __bf16* __restrict__ Q, int ldq,
    const __bf16* __restrict__ K, int ldk,
    const __bf16* __restrict__ VT, int lenKV,
    __bf16* __restrict__ Oout, int ldo,
    const int* __restrict__ pb, const int* __restrict__ pp,
    const int* __restrict__ tb, const int* __restrict__ tp)
{
  __shared__ __align__(16) char KsB[64 * 512];
  __shared__ __align__(16) char VtsB[256 * 128];
  __shared__ __align__(16) char PsB[64 * 128];
  const int tid = threadIdx.x;
  const int lane = tid & 63, wave = tid >> 6;
  const int fr = lane & 15, fq = lane >> 4;
  const int sw7 = fr & 7;
  const int q0 = blockIdx.x << 6;
  const int h = blockIdx.y;
  const __bf16* Qh = Q + (size_t)h * DHEAD;
  const __bf16* Kh = K + (size_t)h * DHEAD;
  const __bf16* VTh = VT + (size_t)h * DHEAD * lenKV;

  int qb_l, aux_l;
  if (MODE == 0) { qb_l = pb[q0 + lane]; aux_l = pp[q0 + lane]; }
  else           { qb_l = tb[q0 + lane]; aux_l = tp[((q0 + lane) >> 4) << 4]; }
  const int qb0 = __shfl(qb_l, 0);
  const bool uniform = __all(qb_l == qb0);
  int amax = aux_l;
#pragma unroll
  for (int s = 1; s < 64; s <<= 1) amax = max(amax, __shfl_xor(amax, s));

  const int q_s = q0 + (wave << 4) + fr;
  int qb_s, aux_s;
  if (MODE == 0) { qb_s = pb[q_s]; aux_s = pp[q_s]; }
  else           { qb_s = tb[q_s]; aux_s = tp[(q_s >> 4) << 4]; }
  const int qblk_s = q_s >> 4;

  bf16x8 qreg[8];
#pragma unroll
  for (int ds = 0; ds < 8; ++ds)
    qreg[ds] = *reinterpret_cast<const bf16x8*>(
        Qh + (size_t)q_s * ldq + (ds << 5) + (fq << 3));

  f32x4 acc[16] = {};
  float mrun = -1.0e30f, lrun = 0.0f;

  for (int kv0 = 0; kv0 < lenKV; kv0 += 64) {
    bool ok;
    if (MODE == 0) {
      ok = (pb[kv0 + lane] == qb0) && (pp[kv0 + lane] <= amax);
    } else if (kv0 < P_TOK) {
      ok = (pb[kv0 + lane] == qb0) && (pp[kv0 + lane] < amax);
    } else {
      const int kk = kv0 - P_TOK + lane;
      const int kb = kk >> 4;
      ok = (tb[kk] == qb0) && (kb >= (q0 >> 4)) && (kb <= ((q0 + 63) >> 4));
    }
    if (uniform && !__any(ok)) continue;

    __syncthreads();
#pragma unroll
    for (int i = 0; i < 8; ++i) {
      const int s = wave + (i << 2);
      const int cl = (s << 6) + lane;
      {
        const int r = cl >> 5, c = cl & 31;
        gload16(Kh + (size_t)(kv0 + r) * ldk + ((c ^ (r & 7)) << 3), KsB + (s << 10));
      }
      {
        const int rd = cl >> 3, c = cl & 7;
        gload16(VTh + (size_t)rd * lenKV + kv0 + ((c ^ (rd & 7)) << 3), VtsB + (s << 10));
      }
    }
    __syncthreads();

    f32x4 st[4] = {};
#pragma unroll
    for (int ds = 0; ds < 8; ++ds) {
#pragma unroll
      for (int mt = 0; mt < 4; ++mt) {
        const bf16x8 kf = *reinterpret_cast<const bf16x8*>(
            KsB + ((mt << 4) + fr) * 512 + ((((ds << 2) + fq) ^ sw7) << 4));
        st[mt] = __builtin_amdgcn_mfma_f32_16x16x32_bf16(kf, qreg[ds], st[mt], 0, 0, 0);
      }
    }

    float pv[16];
    float tmax = -3.0e38f;
#pragma unroll
    for (int mt = 0; mt < 4; ++mt) {
      const int kbase = kv0 + (mt << 4) + (fq << 2);
      bool vis[4];
      if (MODE == 0) {
        const int4 pbv = *reinterpret_cast<const int4*>(pb + kbase);
        const int4 ppv = *reinterpret_cast<const int4*>(pp + kbase);
        vis[0] = (pbv.x == qb_s) && (aux_s >= ppv.x);
        vis[1] = (pbv.y == qb_s) && (aux_s >= ppv.y);
        vis[2] = (pbv.z == qb_s) && (aux_s >= ppv.z);
        vis[3] = (pbv.w == qb_s) && (aux_s >= ppv.w);
      } else if (kv0 < P_TOK) {
        const int4 pbv = *reinterpret_cast<const int4*>(pb + kbase);
        const int4 ppv = *reinterpret_cast<const int4*>(pp + kbase);
        vis[0] = (pbv.x == qb_s) && (aux_s > ppv.x);
        vis[1] = (pbv.y == qb_s) && (aux_s > ppv.y);
        vis[2] = (pbv.z == qb_s) && (aux_s > ppv.z);
        vis[3] = (pbv.w == qb_s) && (aux_s > ppv.w);
      } else {
        const int4 tbv = *reinterpret_cast<const int4*>(tb + kbase - P_TOK);
        const bool blkok = (((kv0 - P_TOK) >> 4) + mt) == qblk_s;
        vis[0] = (tbv.x == qb_s) && blkok;
        vis[1] = (tbv.y == qb_s) && blkok;
        vis[2] = (tbv.z == qb_s) && blkok;
        vis[3] = (tbv.w == qb_s) && blkok;
      }
#pragma unroll
      for (int r = 0; r < 4; ++r) {
        const float sv = st[mt][r] * 0.0625f;
        const float val = vis[r] ? sv : -1.0e30f;
        pv[(mt << 2) + r] = val;
        tmax = fmaxf(tmax, val);
      }
    }
    tmax = fmaxf(tmax, __shfl_xor(tmax, 16));
    tmax = fmaxf(tmax, __shfl_xor(tmax, 32));

    const float m_old = mrun;
    const bool grow = tmax > m_old + 8.0f;
    const float mnew = grow ? tmax : m_old;
    float tsum = 0.f;
#pragma unroll
    for (int i = 0; i < 16; ++i) { pv[i] = __expf(pv[i] - mnew); tsum += pv[i]; }
    tsum += __shfl_xor(tsum, 16);
    tsum += __shfl_xor(tsum, 32);
    const float fac = __expf(m_old - mnew);
    lrun = lrun * fac + tsum;
    mrun = mnew;

#pragma unroll
    for (int mt = 0; mt < 4; ++mt) {
#pragma unroll
      for (int rp = 0; rp < 4; rp += 2) {
        const unsigned u = pack_bf2(pv[(mt << 2) + rp], pv[(mt << 2) + rp + 1]);
        *reinterpret_cast<unsigned*>(PsB + ((wave << 4) + fr) * 128
            + ((((mt << 1) + (fq >> 1)) ^ sw7) << 4) + ((fq & 1) << 3) + ((rp >> 1) << 2)) = u;
      }
    }

    if (!__all(!grow)) {
#pragma unroll
      for (int r = 0; r < 4; ++r) {
        const float f_r = __shfl(fac, ((lane >> 4) << 2) + r);
#pragma unroll
        for (int dt = 0; dt < 16; ++dt) acc[dt][r] *= f_r;
      }
    }

#pragma unroll
    for (int kk = 0; kk < 2; ++kk) {
      const bf16x8 pa = *reinterpret_cast<const bf16x8*>(
          PsB + ((wave << 4) + fr) * 128 + ((((kk << 2) + fq) ^ sw7) << 4));
#pragma unroll
      for (int dt = 0; dt < 16; ++dt) {
        const bf16x8 vb = *reinterpret_cast<const bf16x8*>(
            VtsB + ((dt << 4) + fr) * 128 + ((((kk << 2) + fq) ^ sw7) << 4));
        acc[dt] = __builtin_amdgcn_mfma_f32_16x16x32_bf16(pa, vb, acc[dt], 0, 0, 0);
      }
    }
  }

#pragma unroll
  for (int r = 0; r < 4; ++r) {
    const float linv = 1.0f / __shfl(lrun, ((lane >> 4) << 2) + r);
    const int rowg = q0 + (wave << 4) + (fq << 2) + r;
#pragma unroll
    for (int dt = 0; dt < 16; ++dt)
      Oout[(size_t)rowg * ldo + (size_t)h * DHEAD + (dt << 4) + fr] = (__bf16)(acc[dt][r] * linv);
  }
}

// ---------------------------------------------------------------------------
// Batched weight-set transpose: one dispatch per weight set.
// ---------------------------------------------------------------------------
__global__ __launch_bounds__(256) void transpose_set(
    const float* __restrict__ sQkv, const float* __restrict__ sO,
    const float* __restrict__ sM1, const float* __restrict__ sM2,
    __bf16* __restrict__ dstBase)
{
  int b = blockIdx.x;
  const float* src; long doff; int R, Cc;
  if (b < 12288)      { src = sQkv; R = DIM;   Cc = 3 * DIM; doff = 0; }
  else if (b < 16384) { b -= 12288; src = sO;  R = DIM; Cc = DIM;
                        doff = (long)3 * DIM * DIM; }
  else if (b < 32768) { b -= 16384; src = sM1; R = DIM; Cc = FFDIM;
                        doff = (long)3 * DIM * DIM + (long)DIM * DIM; }
  else                { b -= 32768; src = sM2; R = FFDIM; Cc = DIM;
                        doff = (long)3 * DIM * DIM + (long)DIM * DIM + (long)DIM * FFDIM; }
  __bf16* dst = dstBase + doff;
  const int tilesX = Cc >> 5;
  const int bx = (b % tilesX) << 5, by = (b / tilesX) << 5;
  __shared__ float tile[32][33];
  const int tx = threadIdx.x & 31, ty = threadIdx.x >> 5;
#pragma unroll
  for (int k = 0; k < 32; k += 8)
    tile[ty + k][tx] = src[(size_t)(by + ty + k) * Cc + bx + tx];
  __syncthreads();
#pragma unroll
  for (int k = 0; k < 32; k += 8)
    dst[(size_t)(bx + ty + k) * R + by + tx] = (__bf16)tile[tx][ty + k];
}

__global__ __launch_bounds__(256) void conv_bf16(const float* __restrict__ src,
    __bf16* __restrict__ dst, long n8)
{
  const long i = (long)blockIdx.x * 256 + threadIdx.x;
  if (i >= n8) return;
  const float4 a = reinterpret_cast<const float4*>(src)[i * 2];
  const float4 b = reinterpret_cast<const float4*>(src)[i * 2 + 1];
  bf16x8 h;
  h[0] = (__bf16)a.x; h[1] = (__bf16)a.y; h[2] = (__bf16)a.z; h[3] = (__bf16)a.w;
  h[4] = (__bf16)b.x; h[5] = (__bf16)b.y; h[6] = (__bf16)b.z; h[7] = (__bf16)b.w;
  reinterpret_cast<bf16x8*>(dst)[i] = h;
}

__global__ __launch_bounds__(256) void rms_bf16(const float* __restrict__ x,
    const float* __restrict__ g, __bf16* __restrict__ y, const int* __restrict__ row_idx)
{
  __shared__ float red[256];
  const int r = blockIdx.x;
  const int src = row_idx ? row_idx[r] : r;
  const float* xr = x + (size_t)src * DIM;
  __bf16* yr = y + (size_t)r * DIM;
  const int t = threadIdx.x;
  const float4 v0 = *reinterpret_cast<const float4*>(xr + t * 8);
  const float4 v1 = *reinterpret_cast<const float4*>(xr + t * 8 + 4);
  float ss = v0.x * v0.x + v0.y * v0.y + v0.z * v0.z + v0.w * v0.w
           + v1.x * v1.x + v1.y * v1.y + v1.z * v1.z + v1.w * v1.w;
  red[t] = ss; __syncthreads();
  for (int s = 128; s > 0; s >>= 1) { if (t < s) red[t] += red[t + s]; __syncthreads(); }
  const float inv = rsqrtf(red[0] * (1.0f / DIM) + 1e-6f);
  const float4 g0 = *reinterpret_cast<const float4*>(g + t * 8);
  const float4 g1 = *reinterpret_cast<const float4*>(g + t * 8 + 4);
  bf16x8 h;
  h[0] = (__bf16)(v0.x * g0.x * inv); h[1] = (__bf16)(v0.y * g0.y * inv);
  h[2] = (__bf16)(v0.z * g0.z * inv); h[3] = (__bf16)(v0.w * g0.w * inv);
  h[4] = (__bf16)(v1.x * g1.x * inv); h[5] = (__bf16)(v1.y * g1.y * inv);
  h[6] = (__bf16)(v1.z * g1.z * inv); h[7] = (__bf16)(v1.w * g1.w * inv);
  *reinterpret_cast<bf16x8*>(yr + t * 8) = h;
}

__global__ __launch_bounds__(256) void gather_rows_kernel(const float* __restrict__ tab,
    const int* __restrict__ ids, float* __restrict__ out)
{
  const int r = blockIdx.x;
  const float* src = tab + (size_t)ids[r] * DIM;
  float* dst = out + (size_t)r * DIM;
  const int t = threadIdx.x;
  *reinterpret_cast<float4*>(dst + t * 8) = *reinterpret_cast<const float4*>(src + t * 8);
  *reinterpret_cast<float4*>(dst + t * 8 + 4) = *reinterpret_cast<const float4*>(src + t * 8 + 4);
}

// ---------------------------------------------------------------------------
__global__ __launch_bounds__(256) void teacher_softmax_kernel(const float* __restrict__ TL,
    __bf16* __restrict__ PT, float* __restrict__ ENT, float* __restrict__ S1)
{
  __shared__ float sm[256], ss[256];
  const int r = blockIdx.x, t = threadIdx.x;
  const float* tl = TL + (size_t)r * VOCAB;
  __bf16* pt = PT + (size_t)r * VOCAB;
  float m = -3.0e38f, s = 0.f;
  for (int v = t; v < VOCAB; v += 256) {
    const float x = tl[v];
    if (x > m) { s = s * expf(m - x) + 1.f; m = x; }
    else       { s += expf(x - m); }
  }
  sm[t] = m; ss[t] = s; __syncthreads();
  for (int st = 128; st > 0; st >>= 1) {
    if (t < st) {
      const float m2 = sm[t + st], s2 = ss[t + st];
      const float M = fmaxf(sm[t], m2);
      ss[t] = ss[t] * expf(sm[t] - M) + s2 * expf(m2 - M);
      sm[t] = M;
    }
    __syncthreads();
  }
  const float Mt = sm[0], Z = ss[0];
  const float invZ = 1.0f / Z, lZ = logf(Z);
  __syncthreads();
  float ent = 0.f, s1 = 0.f;
  for (int v = t; v < VOCAB; v += 256) {
    const float x = tl[v];
    const float p = expf(x - Mt) * invZ;
    const __bf16 pb_ = (__bf16)p;
    pt[v] = pb_;
    const float pf = (float)pb_;
    ent += pf * (x - Mt - lZ);
    s1 += pf;
  }
  sm[t] = ent; ss[t] = s1; __syncthreads();
  for (int st = 128; st > 0; st >>= 1) {
    if (t < st) { sm[t] += sm[t + st]; ss[t] += ss[t + st]; }
    __syncthreads();
  }
  if (t == 0) { ENT[r] = sm[0]; S1[r] = ss[0]; }
}

// KD loss, single pass over DL: online-LSE + cross-term simultaneously.
__global__ __launch_bounds__(256) void kl_loss_kernel(const float* __restrict__ DL,
    const __bf16* __restrict__ PT, const float* __restrict__ ENT, const float* __restrict__ S1,
    const int* __restrict__ labels, const int* __restrict__ nitems, float* __restrict__ out)
{
  __shared__ float sm[256], ss[256], sc[256];
  const int r = blockIdx.x, t = threadIdx.x;
  if (labels[r] == -100) return;
  const float* dl = DL + (size_t)r * VOCAB;
  const __bf16* pt = PT + (size_t)r * VOCAB;
  float m = -3.0e38f, s = 0.f, cross = 0.f;
  for (int v = t; v < VOCAB; v += 256) {
    const float x = dl[v];
    cross += (float)pt[v] * x;
    if (x > m) { s = s * expf(m - x) + 1.f; m = x; }
    else       { s += expf(x - m); }
  }
  sm[t] = m; ss[t] = s; sc[t] = cross; __syncthreads();
  for (int st = 128; st > 0; st >>= 1) {
    if (t < st) {
      const float m2 = sm[t + st], s2 = ss[t + st];
      const float M = fmaxf(sm[t], m2);
      ss[t] = ss[t] * expf(sm[t] - M) + s2 * expf(m2 - M);
      sm[t] = M;
      sc[t] += sc[t + st];
    }
    __syncthreads();
  }
  if (t == 0) {
    const float lses = sm[0] + logf(ss[0]);
    const int raw = nitems[0];
    const float n = (raw > 0 && raw < 1000000) ? (float)raw : __int_as_float(raw);
    const float loss_r = ENT[r] - sc[0] + lses * S1[r];
    atomicAdd(out, loss_r / n);
  }
}

// ---------------------------------------------------------------------------
template<typename CT, bool ACCUM, int EPI>
static inline void g128(const __bf16* A, const __bf16* B, CT* C,
                        int M, int N, int K, int lda, int ldb, int ldc, hipStream_t s)
{
  gemm_bt<CT, ACCUM, EPI><<<dim3(N / 128, M / 128), 256, 0, s>>>(A, B, C, M, N, K, lda, ldb, ldc);
}

extern "C" void kernel_launch(void* const* d_in, const int* in_sizes, int n_in,
                              void* d_out, int out_size, void* d_ws, size_t ws_size,
                              hipStream_t stream)
{
  const int* prefix_ids = (const int*)d_in[0];
  const int* pb        = (const int*)d_in[1];
  const int* pp        = (const int*)d_in[2];
  const int* input_ids = (const int*)d_in[3];
  const int* tb        = (const int*)d_in[4];
  const int* tp        = (const int*)d_in[5];
  const int* tgi       = (const int*)d_in[6];
  const int* labels    = (const int*)d_in[7];
  const int* nitems    = (const int*)d_in[8];
  const float* Wt_embed = (const float*)d_in[9];
  const float* Wt_qkv   = (const float*)d_in[10];
  const float* Wt_o     = (const float*)d_in[11];
  const float* Wt_m1    = (const float*)d_in[12];
  const float* Wt_m2    = (const float*)d_in[13];
  const float* gt_ln1   = (const float*)d_in[14];
  const float* gt_ln2   = (const float*)d_in[15];
  const float* gt_lnf   = (const float*)d_in[16];
  const float* Wd_embed = (const float*)d_in[17];
  const float* Wd_qkv   = (const float*)d_in[18];
  const float* Wd_o     = (const float*)d_in[19];
  const float* Wd_m1    = (const float*)d_in[20];
  const float* Wd_m2    = (const float*)d_in[21];
  const float* gd_ln1   = (const float*)d_in[22];
  const float* gd_ln2   = (const float*)d_in[23];
  const float* gd_lnf   = (const float*)d_in[24];

  // ---------------- workspace layout (bytes) ----------------
  char* base = (char*)d_ws;
  size_t off = 0;
  auto alloc = [&](size_t bytes) { size_t o = off; off += (bytes + 255) & ~(size_t)255; return o; };
  const size_t oX    = alloc((size_t)P_TOK * DIM * 4);
  const size_t oXNb  = alloc((size_t)KV_TOK * DIM * 2);
  const size_t oQKVb = alloc((size_t)P_TOK * 3 * DIM * 2);
  const size_t oOb   = alloc((size_t)P_TOK * DIM * 2);
  const size_t oVT   = alloc((size_t)DIM * KV_TOK * 2);
  const size_t oMHb  = alloc((size_t)P_TOK * FFDIM * 2);
  const size_t oY    = alloc((size_t)T_TOK * DIM * 4);
  const size_t oPT   = alloc((size_t)T_TOK * VOCAB * 2);
  const size_t oENT  = alloc((size_t)T_TOK * 4);
  const size_t oS1   = alloc((size_t)T_TOK * 4);
  const size_t oEMB  = alloc((size_t)VOCAB * DIM * 2);
  const size_t oWB   = alloc((size_t)(3 * DIM * DIM + DIM * DIM + DIM * FFDIM + FFDIM * DIM) * 2);
  if (ws_size < off) return;

  float*  X    = (float*)(base + oX);
  __bf16* XNb  = (__bf16*)(base + oXNb);
  __bf16* QKVb = (__bf16*)(base + oQKVb);
  __bf16* Ob   = (__bf16*)(base + oOb);
  __bf16* VT   = (__bf16*)(base + oVT);
  __bf16* MHb  = (__bf16*)(base + oMHb);
  float*  Y    = (float*)(base + oY);
  __bf16* PT   = (__bf16*)(base + oPT);
  float*  ENT  = (float*)(base + oENT);
  float*  S1   = (float*)(base + oS1);
  __bf16* embB = (__bf16*)(base + oEMB);
  __bf16* wQkvT = (__bf16*)(base + oWB);                 // [3D, D] rows: q | k | v
  __bf16* wOT   = wQkvT + (size_t)3 * DIM * DIM;         // [D, D]
  __bf16* wM1T  = wOT + (size_t)DIM * DIM;               // [FF, D]
  __bf16* wM2T  = wM1T + (size_t)FFDIM * DIM;            // [D, FF]
  float*  TLOG = (float*)(base + oQKVb);   // overlay (QKVb..MHb dead at logit time)
  float*  DLOG = (float*)(base + oQKVb);

  hipMemsetAsync(d_out, 0, sizeof(float), stream);

  // ---------------- target causal prefill ----------------
  gather_rows_kernel<<<P_TOK, 256, 0, stream>>>(Wt_embed, prefix_ids, X);
  for (int l = 0; l < NLAYER; ++l) {
    transpose_set<<<49152, 256, 0, stream>>>(
        Wt_qkv + (size_t)l * DIM * 3 * DIM, Wt_o + (size_t)l * DIM * DIM,
        Wt_m1 + (size_t)l * DIM * FFDIM, Wt_m2 + (size_t)l * FFDIM * DIM, wQkvT);

    rms_bf16<<<P_TOK, 256, 0, stream>>>(X, gt_ln1 + l * DIM, XNb, nullptr);
    // QK: [P, 2D] (q | k); V^T directly via GEMM
    g128<__bf16, false, 0>(XNb, wQkvT, QKVb, P_TOK, 2 * DIM, DIM, DIM, DIM, 2 * DIM, stream);
    g128<__bf16, false, 0>(wQkvT + (size_t)2 * DIM * DIM, XNb, VT,
                           DIM, P_TOK, DIM, DIM, DIM, P_TOK, stream);           // VT [D, P]
    flash_attn<0><<<dim3(P_TOK / 64, NHEAD), 256, 0, stream>>>(
        QKVb, 2 * DIM, QKVb + DIM, 2 * DIM, VT, P_TOK, Ob, DIM, pb, pp, nullptr, nullptr);
    g128<float, true, 0>(Ob, wOT, X, P_TOK, DIM, DIM, DIM, DIM, DIM, stream);   // X += attn@Wo
    rms_bf16<<<P_TOK, 256, 0, stream>>>(X, gt_ln2 + l * DIM, XNb, nullptr);
    g128<__bf16, false, 1>(XNb, wM1T, MHb, P_TOK, FFDIM, DIM, DIM, DIM, FFDIM, stream); // +gelu
    g128<float, true, 0>(MHb, wM2T, X, P_TOK, DIM, FFDIM, FFDIM, FFDIM, DIM, stream);   // X += mlp
  }

  // ---------------- teacher logits -> PT/ENT/S1 ----------------
  rms_bf16<<<T_TOK, 256, 0, stream>>>(X, gt_lnf, XNb, tgi);
  conv_bf16<<<((long)VOCAB * DIM / 8 + 255) / 256, 256, 0, stream>>>(Wt_embed, embB, (long)VOCAB * DIM / 8);
  g128<float, false, 0>(XNb, embB, TLOG, T_TOK, VOCAB, DIM, DIM, DIM, VOCAB, stream);
  teacher_softmax_kernel<<<T_TOK, 256, 0, stream>>>(TLOG, PT, ENT, S1);

  // ---------------- draft forward ----------------
  gather_rows_kernel<<<T_TOK, 256, 0, stream>>>(Wd_embed, input_ids, Y);
  transpose_set<<<49152, 256, 0, stream>>>(Wd_qkv, Wd_o, Wd_m1, Wd_m2, wQkvT);

  rms_bf16<<<P_TOK, 256, 0, stream>>>(X, gd_ln1, XNb, nullptr);                       // xkv_n[0:P]
  rms_bf16<<<T_TOK, 256, 0, stream>>>(Y, gd_ln1, XNb + (size_t)P_TOK * DIM, nullptr); // xq_n
  __bf16* Qb = QKVb;                                 // [T, D]
  __bf16* Kb = QKVb + (size_t)T_TOK * DIM;           // [KV, D]
  g128<__bf16, false, 0>(XNb + (size_t)P_TOK * DIM, wQkvT, Qb, T_TOK, DIM, DIM, DIM, DIM, DIM, stream);
  g128<__bf16, false, 0>(XNb, wQkvT + (size_t)DIM * DIM, Kb, KV_TOK, DIM, DIM, DIM, DIM, DIM, stream);
  g128<__bf16, false, 0>(wQkvT + (size_t)2 * DIM * DIM, XNb, VT,
                         DIM, KV_TOK, DIM, DIM, DIM, KV_TOK, stream);           // VTd [D, KV]
  flash_attn<1><<<dim3(T_TOK / 64, NHEAD), 256, 0, stream>>>(
      Qb, DIM, Kb, DIM, VT, KV_TOK, Ob, DIM, pb, pp, tb, tp);
  g128<float, true, 0>(Ob, wOT, Y, T_TOK, DIM, DIM, DIM, DIM, DIM, stream);     // y = xq + attn@Wo
  rms_bf16<<<T_TOK, 256, 0, stream>>>(Y, gd_ln2, XNb, nullptr);
  g128<__bf16, false, 1>(XNb, wM1T, MHb, T_TOK, FFDIM, DIM, DIM, DIM, FFDIM, stream);  // +gelu
  g128<float, true, 0>(MHb, wM2T, Y, T_TOK, DIM, FFDIM, FFDIM, FFDIM, DIM, stream);    // y += mlp
  rms_bf16<<<T_TOK, 256, 0, stream>>>(Y, gd_lnf, XNb, nullptr);
  conv_bf16<<<((long)VOCAB * DIM / 8 + 255) / 256, 256, 0, stream>>>(Wd_embed, embB, (long)VOCAB * DIM / 8);
  g128<float, false, 0>(XNb, embB, DLOG, T_TOK, VOCAB, DIM, DIM, DIM, VOCAB, stream);

  // ---------------- KD loss ----------------
  kl_loss_kernel<<<T_TOK, 256, 0, stream>>>(DLOG, PT, ENT, S1, labels, nitems, (float*)d_out);
}